// Round 1
// baseline (115.143 us; speedup 1.0000x reference)
//
#include <hip/hip_runtime.h>
#include <cmath>

#define T_SEQ 4096
#define D_MODEL 1024
#define HD 64
#define EPS 1e-6f

// elu(x)+1 : x>0 ? x+1 : exp(x)
__device__ __forceinline__ float elu1(float x) {
    return x > 0.f ? x + 1.f : __expf(x);
}

// ---------------------------------------------------------------------------
// Kernel A: partial context per (head, chunk).
// grid = 64 heads * 8 chunks, block = 256 (4 waves).
// Each block covers 512 rows; per 64-row LDS tile, wave w accumulates rows
// [w*16, w*16+16) into its own full 64x64 accumulator (8x8 per lane).
// Cross-wave reduce in LDS, then write 4096 ctx + 64 ksum floats to ws.
// ---------------------------------------------------------------------------
__global__ __launch_bounds__(256) void ctx_partial(const float* __restrict__ K,
                                                   const float* __restrict__ V,
                                                   float* __restrict__ partial) {
    __shared__ float sK[64 * 64];
    __shared__ float sV[64 * 64];
    __shared__ float sKs[128];

    const int head  = blockIdx.x >> 3;   // 0..63
    const int chunk = blockIdx.x & 7;    // 0..7
    const int b = head >> 4, h = head & 15;
    const int tid  = threadIdx.x;
    const int wave = tid >> 6, lane = tid & 63;
    const int le = lane >> 3, ld = lane & 7;

    const size_t base = ((size_t)b * T_SEQ) * D_MODEL + (size_t)h * HD;
    const int s0 = chunk * 512;

    float acc[8][8];
    float ks[8];
#pragma unroll
    for (int i = 0; i < 8; ++i) {
        ks[i] = 0.f;
#pragma unroll
        for (int j = 0; j < 8; ++j) acc[i][j] = 0.f;
    }

    for (int it = 0; it < 8; ++it) {
        const int r0 = s0 + it * 64;
        // --- stage 64 rows of K (with elu+1) and V, coalesced float4 ---
#pragma unroll
        for (int li = 0; li < 4; ++li) {
            const int lin = tid + li * 256;          // float4 index [0,1024)
            const int row = lin >> 4, c4 = lin & 15;
            const size_t g = base + (size_t)(r0 + row) * D_MODEL + c4 * 4;
            float4 kv = *(const float4*)(K + g);
            float4 vv = *(const float4*)(V + g);
            kv.x = elu1(kv.x); kv.y = elu1(kv.y);
            kv.z = elu1(kv.z); kv.w = elu1(kv.w);
            *(float4*)&sK[row * 64 + c4 * 4] = kv;
            *(float4*)&sV[row * 64 + c4 * 4] = vv;
        }
        __syncthreads();

        // --- accumulate: wave w takes staged rows [w*16, w*16+16) ---
#pragma unroll
        for (int s = 0; s < 16; ++s) {
            const int sr = wave * 16 + s;
            const float4 ka = *(const float4*)&sK[sr * 64 + 8 * le];
            const float4 kb = *(const float4*)&sK[sr * 64 + 8 * le + 4];
            const float4 va = *(const float4*)&sV[sr * 64 + 8 * ld];
            const float4 vb = *(const float4*)&sV[sr * 64 + 8 * ld + 4];
            const float kf[8] = {ka.x, ka.y, ka.z, ka.w, kb.x, kb.y, kb.z, kb.w};
            const float vf[8] = {va.x, va.y, va.z, va.w, vb.x, vb.y, vb.z, vb.w};
#pragma unroll
            for (int i = 0; i < 8; ++i) {
                ks[i] += kf[i];
#pragma unroll
                for (int j = 0; j < 8; ++j) acc[i][j] = fmaf(kf[i], vf[j], acc[i][j]);
            }
        }
        __syncthreads();
    }

    // --- cross-wave reduction ---
    // phase 1: waves 2,3 dump; waves 0,1 add.
    if (wave >= 2) {
        float* dst = (wave == 2) ? sK : sV;
#pragma unroll
        for (int i = 0; i < 8; ++i)
#pragma unroll
            for (int j = 0; j < 8; ++j) dst[(i * 8 + j) * 64 + lane] = acc[i][j];
        if (ld == 0) {
#pragma unroll
            for (int i = 0; i < 8; ++i) sKs[(wave - 2) * 64 + 8 * le + i] = ks[i];
        }
    }
    __syncthreads();
    if (wave < 2) {
        const float* src = (wave == 0) ? sK : sV;
#pragma unroll
        for (int i = 0; i < 8; ++i)
#pragma unroll
            for (int j = 0; j < 8; ++j) acc[i][j] += src[(i * 8 + j) * 64 + lane];
        if (ld == 0) {
#pragma unroll
            for (int i = 0; i < 8; ++i) ks[i] += sKs[wave * 64 + 8 * le + i];
        }
    }
    __syncthreads();
    // phase 2: wave 1 dumps; wave 0 adds + stores.
    if (wave == 1) {
#pragma unroll
        for (int i = 0; i < 8; ++i)
#pragma unroll
            for (int j = 0; j < 8; ++j) sK[(i * 8 + j) * 64 + lane] = acc[i][j];
        if (ld == 0) {
#pragma unroll
            for (int i = 0; i < 8; ++i) sKs[8 * le + i] = ks[i];
        }
    }
    __syncthreads();
    if (wave == 0) {
#pragma unroll
        for (int i = 0; i < 8; ++i)
#pragma unroll
            for (int j = 0; j < 8; ++j) acc[i][j] += sK[(i * 8 + j) * 64 + lane];
        float* outp = partial + (size_t)blockIdx.x * 4160;
#pragma unroll
        for (int i = 0; i < 8; ++i) {
            const float4 a = make_float4(acc[i][0], acc[i][1], acc[i][2], acc[i][3]);
            const float4 c = make_float4(acc[i][4], acc[i][5], acc[i][6], acc[i][7]);
            *(float4*)&outp[(8 * le + i) * 64 + 8 * ld]     = a;
            *(float4*)&outp[(8 * le + i) * 64 + 8 * ld + 4] = c;
        }
        if (ld == 0) {
#pragma unroll
            for (int i = 0; i < 8; ++i) ks[i] += sKs[8 * le + i];
            *(float4*)&outp[4096 + 8 * le]     = make_float4(ks[0], ks[1], ks[2], ks[3]);
            *(float4*)&outp[4096 + 8 * le + 4] = make_float4(ks[4], ks[5], ks[6], ks[7]);
        }
    }
}

// ---------------------------------------------------------------------------
// Kernel A2: reduce 8 chunk partials -> final ctx per head. grid = 64.
// ---------------------------------------------------------------------------
__global__ __launch_bounds__(256) void ctx_reduce(const float* __restrict__ partial,
                                                  float* __restrict__ ctx) {
    const int head = blockIdx.x;
    for (int idx = threadIdx.x; idx < 4160; idx += 256) {
        float s = 0.f;
#pragma unroll
        for (int c = 0; c < 8; ++c)
            s += partial[((size_t)head * 8 + c) * 4160 + idx];
        ctx[(size_t)head * 4160 + idx] = s;
    }
}

// ---------------------------------------------------------------------------
// Kernel B: out[n][d] = (Q'[n]·ctx)[d] * 1/(Q'[n]·ksum + eps)
// grid = 64 heads * 16 row-blocks, block = 256 (4 waves, 64 rows each).
// Lane tile: 8 rows x 8 cols. Q read direct from global; ctx+ksum in LDS.
// ---------------------------------------------------------------------------
__global__ __launch_bounds__(256) void attn_out(const float* __restrict__ Q,
                                                const float* __restrict__ ctx,
                                                float* __restrict__ out) {
    __shared__ float sC[4160];
    const int head = blockIdx.x >> 4;
    const int nb   = blockIdx.x & 15;
    const int b = head >> 4, h = head & 15;
    const int tid = threadIdx.x;

    for (int idx = tid; idx < 4160; idx += 256)
        sC[idx] = ctx[(size_t)head * 4160 + idx];
    __syncthreads();

    const int wave = tid >> 6, lane = tid & 63;
    const int ln = lane >> 3, ld = lane & 7;
    const int n0 = nb * 256 + wave * 64 + 8 * ln;
    const float* qbase = Q + ((size_t)b * T_SEQ + n0) * D_MODEL + h * HD;

    float acc[8][8];
    float D8[8];
#pragma unroll
    for (int i = 0; i < 8; ++i) {
        D8[i] = 0.f;
#pragma unroll
        for (int j = 0; j < 8; ++j) acc[i][j] = 0.f;
    }

    for (int e0 = 0; e0 < 64; e0 += 4) {
        float qs[8][4];
#pragma unroll
        for (int i = 0; i < 8; ++i) {
            float4 v = *(const float4*)(qbase + (size_t)i * D_MODEL + e0);
            qs[i][0] = elu1(v.x); qs[i][1] = elu1(v.y);
            qs[i][2] = elu1(v.z); qs[i][3] = elu1(v.w);
        }
#pragma unroll
        for (int t = 0; t < 4; ++t) {
            const int e = e0 + t;
            const float4 ca = *(const float4*)&sC[e * 64 + 8 * ld];
            const float4 cb = *(const float4*)&sC[e * 64 + 8 * ld + 4];
            const float ksv = sC[4096 + e];
            const float cf[8] = {ca.x, ca.y, ca.z, ca.w, cb.x, cb.y, cb.z, cb.w};
#pragma unroll
            for (int i = 0; i < 8; ++i) {
                const float qv = qs[i][t];
                D8[i] = fmaf(qv, ksv, D8[i]);
#pragma unroll
                for (int j = 0; j < 8; ++j) acc[i][j] = fmaf(qv, cf[j], acc[i][j]);
            }
        }
    }

#pragma unroll
    for (int i = 0; i < 8; ++i) {
        const float dinv = 1.f / (D8[i] + EPS);
        float* op = out + ((size_t)b * T_SEQ + n0 + i) * D_MODEL + h * HD + 8 * ld;
        *(float4*)op       = make_float4(acc[i][0] * dinv, acc[i][1] * dinv,
                                         acc[i][2] * dinv, acc[i][3] * dinv);
        *(float4*)(op + 4) = make_float4(acc[i][4] * dinv, acc[i][5] * dinv,
                                         acc[i][6] * dinv, acc[i][7] * dinv);
    }
}

extern "C" void kernel_launch(void* const* d_in, const int* in_sizes, int n_in,
                              void* d_out, int out_size, void* d_ws, size_t ws_size,
                              hipStream_t stream) {
    const float* Q = (const float*)d_in[0];
    const float* K = (const float*)d_in[1];
    const float* V = (const float*)d_in[2];
    float* out = (float*)d_out;
    float* ws  = (float*)d_ws;

    float* partial = ws;                               // 64*8*4160 floats (~8.5 MB)
    float* ctx     = ws + (size_t)64 * 8 * 4160;       // 64*4160 floats   (~1.1 MB)

    hipLaunchKernelGGL(ctx_partial, dim3(512), dim3(256), 0, stream, K, V, partial);
    hipLaunchKernelGGL(ctx_reduce,  dim3(64),  dim3(256), 0, stream, partial, ctx);
    hipLaunchKernelGGL(attn_out,    dim3(1024), dim3(256), 0, stream, Q, ctx, out);
}

// Round 2
// 73.553 us; speedup vs baseline: 1.5654x; 1.5654x over previous
//
#include <hip/hip_runtime.h>
#include <hip/hip_bf16.h>
#include <cmath>

#define T_SEQ 4096
#define D_MODEL 1024
#define EPS 1e-6f

typedef __attribute__((ext_vector_type(8))) short bf16x8;
typedef __attribute__((ext_vector_type(4))) float f32x4;

__device__ __forceinline__ float elu1(float x) { return x > 0.f ? x + 1.f : __expf(x); }

// float -> bf16 bits, round-to-nearest-even
__device__ __forceinline__ short f2bf(float f) {
    union { float f; unsigned u; } v; v.f = f;
    unsigned r = v.u + 0x7fffu + ((v.u >> 16) & 1u);
    return (short)(r >> 16);
}

// ---------------------------------------------------------------------------
// Kernel A: partial context per (head, chunk) via MFMA.
// grid = 64 heads * 8 chunks, block = 256 (4 waves). Wave w covers 128 s-rows
// (4 k-steps of 32). ctx = K'^T V : A-frag = K'(elu), B-frag = V, both fed
// per-lane direct from global (16 lanes = 64B contiguous per row -> full line
// utilization, L3-resident). 5th B-tile = ones column -> ksum in C layout.
// Cross-wave LDS reduce, write 4096 ctx + 64 ksum floats per block.
// ---------------------------------------------------------------------------
__global__ __launch_bounds__(256) void ctx_partial(const float* __restrict__ K,
                                                   const float* __restrict__ V,
                                                   float* __restrict__ partial) {
    __shared__ float red[2][80 * 64];

    const int head = blockIdx.x >> 3, chunk = blockIdx.x & 7;
    const int b = head >> 4, h = head & 15;
    const int tid = threadIdx.x, wave = tid >> 6, lane = tid & 63;
    const int g = lane >> 4, r = lane & 15;
    const size_t base = ((size_t)b * T_SEQ) * D_MODEL + (size_t)h * 64;

    f32x4 acc[4][5];
#pragma unroll
    for (int m = 0; m < 4; ++m)
#pragma unroll
        for (int n = 0; n < 5; ++n)
#pragma unroll
            for (int q = 0; q < 4; ++q) acc[m][n][q] = 0.f;

    bf16x8 ones;
    const short one_bf = (r == 0) ? (short)0x3F80 : (short)0;
#pragma unroll
    for (int j = 0; j < 8; ++j) ones[j] = one_bf;

    const int s_wave = chunk * 512 + wave * 128;
    for (int kt = 0; kt < 4; ++kt) {
        const int srow = s_wave + kt * 32 + 8 * g;          // + j
        const float* Krow = K + base + (size_t)srow * D_MODEL;
        const float* Vrow = V + base + (size_t)srow * D_MODEL;
        bf16x8 af[4], bf[4];
#pragma unroll
        for (int j = 0; j < 8; ++j) {
            const size_t ro = (size_t)j * D_MODEL;
#pragma unroll
            for (int m = 0; m < 4; ++m) af[m][j] = f2bf(elu1(Krow[ro + 16 * m + r]));
#pragma unroll
            for (int n = 0; n < 4; ++n) bf[n][j] = f2bf(Vrow[ro + 16 * n + r]);
        }
#pragma unroll
        for (int m = 0; m < 4; ++m) {
#pragma unroll
            for (int n = 0; n < 4; ++n)
                acc[m][n] = __builtin_amdgcn_mfma_f32_16x16x32_bf16(af[m], bf[n], acc[m][n], 0, 0, 0);
            acc[m][4] = __builtin_amdgcn_mfma_f32_16x16x32_bf16(af[m], ones, acc[m][4], 0, 0, 0);
        }
    }

    // --- cross-wave reduction (80 f32 per lane) ---
    if (wave >= 2) {
        float* dst = red[wave - 2];
#pragma unroll
        for (int m = 0; m < 4; ++m)
#pragma unroll
            for (int n = 0; n < 5; ++n)
#pragma unroll
                for (int q = 0; q < 4; ++q)
                    dst[((m * 5 + n) * 4 + q) * 64 + lane] = acc[m][n][q];
    }
    __syncthreads();
    if (wave < 2) {
        const float* src = red[wave];
#pragma unroll
        for (int m = 0; m < 4; ++m)
#pragma unroll
            for (int n = 0; n < 5; ++n)
#pragma unroll
                for (int q = 0; q < 4; ++q)
                    acc[m][n][q] += src[((m * 5 + n) * 4 + q) * 64 + lane];
    }
    __syncthreads();
    if (wave == 1) {
        float* dst = red[0];
#pragma unroll
        for (int m = 0; m < 4; ++m)
#pragma unroll
            for (int n = 0; n < 5; ++n)
#pragma unroll
                for (int q = 0; q < 4; ++q)
                    dst[((m * 5 + n) * 4 + q) * 64 + lane] = acc[m][n][q];
    }
    __syncthreads();
    if (wave == 0) {
        const float* src = red[0];
        float* outp = partial + (size_t)blockIdx.x * 4160;
#pragma unroll
        for (int m = 0; m < 4; ++m)
#pragma unroll
            for (int q = 0; q < 4; ++q) {
                const int e = 16 * m + 4 * g + q;
#pragma unroll
                for (int n = 0; n < 4; ++n)
                    outp[e * 64 + 16 * n + r] =
                        acc[m][n][q] + src[((m * 5 + n) * 4 + q) * 64 + lane];
                if (r == 0)
                    outp[4096 + e] = acc[m][4][q] + src[((m * 5 + 4) * 4 + q) * 64 + lane];
            }
    }
}

// ---------------------------------------------------------------------------
// Kernel A2: reduce 8 chunk partials -> final ctx per head. grid = 64.
// ---------------------------------------------------------------------------
__global__ __launch_bounds__(256) void ctx_reduce(const float* __restrict__ partial,
                                                  float* __restrict__ ctx) {
    const int head = blockIdx.x;
    for (int idx = threadIdx.x; idx < 4160; idx += 256) {
        float s = 0.f;
#pragma unroll
        for (int c = 0; c < 8; ++c)
            s += partial[((size_t)head * 8 + c) * 4160 + idx];
        ctx[(size_t)head * 4160 + idx] = s;
    }
}

// ---------------------------------------------------------------------------
// Kernel B: out = (Q' ctx) / (Q' ksum + eps) via MFMA.
// grid = 64 heads * 16 row-chunks, block = 256 (4 waves x 64 rows).
// B-frags (ctx, bf16) loaded once per wave (10 frags, incl. ksum tile 4).
// A-frags: Q loaded float4 per lane, elu+cvt once per element. Denominator
// arrives in C layout of tile n=4; fetched with one shfl from lane (l&48).
// ---------------------------------------------------------------------------
__global__ __launch_bounds__(256) void attn_out(const float* __restrict__ Q,
                                                const float* __restrict__ ctx,
                                                float* __restrict__ out) {
    const int head = blockIdx.x >> 4, nb = blockIdx.x & 15;
    const int b = head >> 4, h = head & 15;
    const int tid = threadIdx.x, wave = tid >> 6, lane = tid & 63;
    const int g = lane >> 4, r = lane & 15;
    const float* C = ctx + (size_t)head * 4160;

    bf16x8 bfr[2][5];
#pragma unroll
    for (int kt = 0; kt < 2; ++kt)
#pragma unroll
        for (int j = 0; j < 8; ++j) {
            const int e = kt * 32 + 8 * g + j;
#pragma unroll
            for (int n = 0; n < 4; ++n) bfr[kt][n][j] = f2bf(C[e * 64 + 16 * n + r]);
            bfr[kt][4][j] = (r == 0) ? f2bf(C[4096 + e]) : (short)0;
        }

    const int n0 = nb * 256 + wave * 64;
    const float* qbase = Q + ((size_t)b * T_SEQ + n0) * D_MODEL + (size_t)h * 64;

    f32x4 acc[4][5];
#pragma unroll
    for (int m = 0; m < 4; ++m)
#pragma unroll
        for (int n = 0; n < 5; ++n)
#pragma unroll
            for (int q = 0; q < 4; ++q) acc[m][n][q] = 0.f;

#pragma unroll
    for (int kt = 0; kt < 2; ++kt)
#pragma unroll
        for (int m = 0; m < 4; ++m) {
            const float* qp = qbase + (size_t)(16 * m + r) * D_MODEL + kt * 32 + 8 * g;
            const float4 q1 = *(const float4*)qp;
            const float4 q2 = *(const float4*)(qp + 4);
            bf16x8 a;
            a[0] = f2bf(elu1(q1.x)); a[1] = f2bf(elu1(q1.y));
            a[2] = f2bf(elu1(q1.z)); a[3] = f2bf(elu1(q1.w));
            a[4] = f2bf(elu1(q2.x)); a[5] = f2bf(elu1(q2.y));
            a[6] = f2bf(elu1(q2.z)); a[7] = f2bf(elu1(q2.w));
#pragma unroll
            for (int n = 0; n < 5; ++n)
                acc[m][n] = __builtin_amdgcn_mfma_f32_16x16x32_bf16(a, bfr[kt][n], acc[m][n], 0, 0, 0);
        }

#pragma unroll
    for (int m = 0; m < 4; ++m) {
        float dinv[4];
#pragma unroll
        for (int q = 0; q < 4; ++q)
            dinv[q] = 1.f / (__shfl(acc[m][4][q], lane & 48) + EPS);
#pragma unroll
        for (int q = 0; q < 4; ++q) {
            float* op = out + ((size_t)b * T_SEQ + n0 + 16 * m + 4 * g + q) * D_MODEL
                        + (size_t)h * 64 + r;
#pragma unroll
            for (int n = 0; n < 4; ++n) op[16 * n] = acc[m][n][q] * dinv[q];
        }
    }
}

extern "C" void kernel_launch(void* const* d_in, const int* in_sizes, int n_in,
                              void* d_out, int out_size, void* d_ws, size_t ws_size,
                              hipStream_t stream) {
    const float* Q = (const float*)d_in[0];
    const float* K = (const float*)d_in[1];
    const float* V = (const float*)d_in[2];
    float* out = (float*)d_out;
    float* ws  = (float*)d_ws;

    float* partial = ws;                               // 512*4160 floats (~8.5 MB)
    float* ctx     = ws + (size_t)512 * 4160;          // 64*4160 floats  (~1.1 MB)

    hipLaunchKernelGGL(ctx_partial, dim3(512),  dim3(256), 0, stream, K, V, partial);
    hipLaunchKernelGGL(ctx_reduce,  dim3(64),   dim3(256), 0, stream, partial, ctx);
    hipLaunchKernelGGL(attn_out,    dim3(1024), dim3(256), 0, stream, Q, ctx, out);
}